// Round 7
// baseline (994.209 us; speedup 1.0000x reference)
//
#include <hip/hip_runtime.h>
#include <hip/hip_bf16.h>
#include <hip/hip_fp16.h>

#define HEADS 3

union HU { uint4 u; __half2 h[4]; };

// ---------------------------------------------------------------- prep: ce[h] = sum_d We[h*D+d] * ae[h*D+d]
__global__ void prep_ce_kernel(const float* __restrict__ We1, const float* __restrict__ ae1,
                               const float* __restrict__ We2, const float* __restrict__ ae2,
                               const float* __restrict__ We3, const float* __restrict__ ae3,
                               float* __restrict__ ce) {
    int t = threadIdx.x;
    if (t >= 9) return;
    int l = t / 3, h = t % 3;
    const float* We = (l == 0) ? We1 : (l == 1) ? We2 : We3;
    const float* ae = (l == 0) ? ae1 : (l == 1) ? ae2 : ae3;
    int D = (l == 0) ? 8 : (l == 1) ? 16 : 32;
    float s = 0.f;
    for (int d = 0; d < D; d++) s += We[h * D + d] * ae[h * D + d];
    ce[t] = s;
}

// ---------------------------------------------------------------- CSR build
// hist + rank in one pass: the atomic's return value is the edge's slot.
__global__ void hist_rank_kernel(const int* __restrict__ dst, int* __restrict__ deg,
                                 int* __restrict__ rank, int E) {
    int tid = blockIdx.x * blockDim.x + threadIdx.x;
    if (tid < E) rank[tid] = atomicAdd(&deg[dst[tid]], 1);
}

#define SCAN_BLK 1024
__global__ void scan1_kernel(const int* __restrict__ deg, int* __restrict__ row_ptr,
                             int* __restrict__ partials, int N) {
    __shared__ int sm[SCAN_BLK];
    int t = threadIdx.x;
    int g = blockIdx.x * SCAN_BLK + t;
    int v = (g < N) ? deg[g] : 0;
    sm[t] = v;
    __syncthreads();
    for (int off = 1; off < SCAN_BLK; off <<= 1) {
        int x = (t >= off) ? sm[t - off] : 0;
        __syncthreads();
        sm[t] += x;
        __syncthreads();
    }
    if (g < N) row_ptr[g] = sm[t] - v;   // exclusive
    if (t == SCAN_BLK - 1) partials[blockIdx.x] = sm[t];
}

__global__ void scan2_kernel(int* __restrict__ partials, int NB) {
    __shared__ int sm[128];
    int t = threadIdx.x;
    int v = (t < NB) ? partials[t] : 0;
    sm[t] = v;
    __syncthreads();
    for (int off = 1; off < 128; off <<= 1) {
        int x = (t >= off) ? sm[t - off] : 0;
        __syncthreads();
        sm[t] += x;
        __syncthreads();
    }
    if (t < NB) partials[t] = sm[t] - v;  // exclusive
    if (t == 127) partials[NB] = sm[127]; // total
}

__global__ void scan3_kernel(int* __restrict__ row_ptr, const int* __restrict__ partials,
                             int N, int NB) {
    int g = blockIdx.x * SCAN_BLK + threadIdx.x;
    if (g < N) row_ptr[g] += partials[blockIdx.x];
    if (blockIdx.x == 0 && threadIdx.x == 0) row_ptr[N] = partials[NB];
}

// atomic-free scatter using precomputed ranks
__global__ void scatter_kernel(const int* __restrict__ src, const int* __restrict__ dst,
                               const float* __restrict__ ef, const int* __restrict__ row_ptr,
                               const int* __restrict__ rank, int2* __restrict__ erec, int E) {
    int tid = blockIdx.x * blockDim.x + threadIdx.x;
    if (tid >= E) return;
    int d = dst[tid];
    int pos = row_ptr[d] + rank[tid];
    int2 r;
    r.x = src[tid];
    r.y = __float_as_int(ef[tid]);
    erec[pos] = r;
}

// ---------------------------------------------------------------- degree-sorted node order
__global__ void degbin_hist_kernel(const int* __restrict__ deg, int* __restrict__ bins, int N) {
    int n = blockIdx.x * blockDim.x + threadIdx.x;
    if (n < N) atomicAdd(&bins[min(deg[n], 63)], 1);
}

__global__ void degbin_scan_kernel(const int* __restrict__ bins, int* __restrict__ bscan) {
    if (threadIdx.x == 0) {
        int run = 0;
        for (int i = 0; i < 64; i++) { bscan[i] = run; run += bins[i]; }
    }
}

__global__ void degbin_scatter_kernel(const int* __restrict__ deg, const int* __restrict__ bscan,
                                      int* __restrict__ bcnt, int* __restrict__ order, int N) {
    int n = blockIdx.x * blockDim.x + threadIdx.x;
    if (n >= N) return;
    int bin = min(deg[n], 63);
    order[bscan[bin] + atomicAdd(&bcnt[bin], 1)] = n;
}

// ---------------------------------------------------------------- node projection: ft (fp16), el, er
template <int FIN, int D, bool MEAN_PREV>
__launch_bounds__(256)
__global__ void node_kernel(const float* __restrict__ xin,
                            const float* __restrict__ W,
                            const float* __restrict__ al,
                            const float* __restrict__ ar,
                            __half* __restrict__ ft,     // [N,3,D] fp16
                            float* __restrict__ el, float* __restrict__ er,
                            int N) {
    int tid = blockIdx.x * blockDim.x + threadIdx.x;
    if (tid >= N * HEADS) return;
    int n = tid / HEADS, h = tid % HEADS;
    float x[FIN];
    if (MEAN_PREV) {
        #pragma unroll
        for (int k = 0; k < FIN; k++)
            x[k] = (xin[(n * HEADS + 0) * FIN + k] +
                    xin[(n * HEADS + 1) * FIN + k] +
                    xin[(n * HEADS + 2) * FIN + k]) * (1.0f / 3.0f);
    } else {
        #pragma unroll
        for (int k = 0; k < FIN; k++) x[k] = xin[n * FIN + k];
    }
    float fv[D];
    float e_l = 0.f, e_r = 0.f;
    #pragma unroll
    for (int d = 0; d < D; d++) {
        const float* wr = &W[(h * D + d) * FIN];
        float f = 0.f;
        #pragma unroll
        for (int k = 0; k < FIN; k++) f += x[k] * wr[k];
        fv[d] = f;
        e_l += f * al[h * D + d];
        e_r += f * ar[h * D + d];
    }
    uint4* dst16 = (uint4*)(ft + (size_t)tid * D);
    #pragma unroll
    for (int q = 0; q < D / 8; q++) {
        HU u;
        #pragma unroll
        for (int j = 0; j < 4; j++)
            u.h[j] = __floats2half2_rn(fv[q * 8 + 2 * j], fv[q * 8 + 2 * j + 1]);
        dst16[q] = u.u;
    }
    el[tid] = e_l;
    er[tid] = e_r;
}

// ---------------------------------------------------------------- attention + aggregate
// 6 lanes per node: (slice s in {0,1}) x (head h in {0,1,2}), h innermost so the
// 3 head-lanes gather one contiguous ft node-group. Nodes come via degree-sorted
// order[] so all nodes in a wave have ~equal degree (no straggler lanes).
// erec loaded only by h==0 lane and broadcast to h=1,2 via shfl (probe dedupe).
template <int D>
__launch_bounds__(256)
__global__ void agg_kernel(const int* __restrict__ row_ptr, const int2* __restrict__ erec,
                           const int* __restrict__ order,
                           const __half* __restrict__ ft,
                           const float* __restrict__ el, const float* __restrict__ er,
                           const float* __restrict__ ce,   // [3] this layer
                           const float* __restrict__ b,    // [3*D]
                           float* __restrict__ out,        // [N,3,D]
                           int N) {
    int w = threadIdx.x >> 6;
    int l = threadIdx.x & 63;
    int wl = l / 6;                 // node slot within wave, 0..9 (l>=60 idle)
    int rem = l - wl * 6;
    int s = rem >= 3 ? 1 : 0;
    int h = rem - s * 3;
    int slot = (blockIdx.x * 4 + w) * 10 + wl;
    bool active = (wl < 10) && (slot < N);
    int n = active ? order[slot] : 0;
    int blane = l - h;              // the h==0 lane of this (node, slice) group

    float m = -3.0e38f, ssum = 0.f;
    float msg[D];
    #pragma unroll
    for (int d = 0; d < D; d++) msg[d] = 0.f;
    int unit = n * HEADS + h;
    float ceh = ce[h];

    if (active) {
        int beg = row_ptr[n], end = row_ptr[n + 1];
        int cnt = end - beg;
        int half = (cnt + 1) >> 1;
        int es = beg + s * half;
        int ee = s ? end : (beg + half);
        float ern = er[unit];

        int e = es;
        for (; e + 3 < ee; e += 4) {
            int2 r0 = make_int2(0, 0), r1 = r0, r2 = r0, r3 = r0;
            if (h == 0) {
                r0 = erec[e + 0]; r1 = erec[e + 1];
                r2 = erec[e + 2]; r3 = erec[e + 3];
            }
            r0.x = __shfl(r0.x, blane); r0.y = __shfl(r0.y, blane);
            r1.x = __shfl(r1.x, blane); r1.y = __shfl(r1.y, blane);
            r2.x = __shfl(r2.x, blane); r2.y = __shfl(r2.y, blane);
            r3.x = __shfl(r3.x, blane); r3.y = __shfl(r3.y, blane);
            float v0 = el[r0.x * HEADS + h] + ern + __int_as_float(r0.y) * ceh;
            float v1 = el[r1.x * HEADS + h] + ern + __int_as_float(r1.y) * ceh;
            float v2 = el[r2.x * HEADS + h] + ern + __int_as_float(r2.y) * ceh;
            float v3 = el[r3.x * HEADS + h] + ern + __int_as_float(r3.y) * ceh;
            v0 = v0 > 0.f ? v0 : 0.2f * v0;
            v1 = v1 > 0.f ? v1 : 0.2f * v1;
            v2 = v2 > 0.f ? v2 : 0.2f * v2;
            v3 = v3 > 0.f ? v3 : 0.2f * v3;
            float cm = fmaxf(fmaxf(v0, v1), fmaxf(v2, v3));
            if (cm > m) {
                float sc = __expf(m - cm);
                ssum *= sc;
                #pragma unroll
                for (int d = 0; d < D; d++) msg[d] *= sc;
                m = cm;
            }
            float x0 = __expf(v0 - m), x1 = __expf(v1 - m);
            float x2 = __expf(v2 - m), x3 = __expf(v3 - m);
            ssum += (x0 + x1) + (x2 + x3);
            const uint4* f0 = (const uint4*)(ft + ((size_t)r0.x * HEADS + h) * D);
            const uint4* f1 = (const uint4*)(ft + ((size_t)r1.x * HEADS + h) * D);
            const uint4* f2 = (const uint4*)(ft + ((size_t)r2.x * HEADS + h) * D);
            const uint4* f3 = (const uint4*)(ft + ((size_t)r3.x * HEADS + h) * D);
            #pragma unroll
            for (int q = 0; q < D / 8; q++) {
                HU a0, a1, a2, a3;
                a0.u = f0[q]; a1.u = f1[q]; a2.u = f2[q]; a3.u = f3[q];
                #pragma unroll
                for (int j = 0; j < 4; j++) {
                    float2 p0 = __half22float2(a0.h[j]);
                    float2 p1 = __half22float2(a1.h[j]);
                    float2 p2 = __half22float2(a2.h[j]);
                    float2 p3 = __half22float2(a3.h[j]);
                    msg[q * 8 + 2 * j + 0] += x0 * p0.x + x1 * p1.x + x2 * p2.x + x3 * p3.x;
                    msg[q * 8 + 2 * j + 1] += x0 * p0.y + x1 * p1.y + x2 * p2.y + x3 * p3.y;
                }
            }
        }
        for (; e < ee; e++) {
            int2 r = erec[e];
            float v = el[r.x * HEADS + h] + ern + __int_as_float(r.y) * ceh;
            v = v > 0.f ? v : 0.2f * v;
            if (v > m) {
                float sc = __expf(m - v);
                ssum *= sc;
                #pragma unroll
                for (int d = 0; d < D; d++) msg[d] *= sc;
                m = v;
            }
            float x = __expf(v - m);
            ssum += x;
            const uint4* fr = (const uint4*)(ft + ((size_t)r.x * HEADS + h) * D);
            #pragma unroll
            for (int q = 0; q < D / 8; q++) {
                HU a; a.u = fr[q];
                #pragma unroll
                for (int j = 0; j < 4; j++) {
                    float2 p = __half22float2(a.h[j]);
                    msg[q * 8 + 2 * j + 0] += x * p.x;
                    msg[q * 8 + 2 * j + 1] += x * p.y;
                }
            }
        }
    }

    // slice-pair combine: partner lane at +/-3
    int pl = (s ? (l - 3) : (l + 3)) & 63;
    float om = __shfl(m, pl);
    float osum = __shfl(ssum, pl);
    float M = fmaxf(m, om);
    float sA = __expf(m - M);
    float sB = __expf(om - M);
    float tot = ssum * sA + osum * sB;
    float inv = 1.0f / fmaxf(tot, 1e-9f);
    #pragma unroll
    for (int d = 0; d < D; d++)
        msg[d] = msg[d] * sA + __shfl(msg[d], pl) * sB;

    if (active) {
        int lo = s * (D / 2);
        float* ob = out + (size_t)unit * D + lo;
        #pragma unroll
        for (int d = 0; d < D / 2; d += 4) {
            float4 v;
            v.x = msg[lo + d + 0] * inv + b[h * D + lo + d + 0];
            v.y = msg[lo + d + 1] * inv + b[h * D + lo + d + 1];
            v.z = msg[lo + d + 2] * inv + b[h * D + lo + d + 2];
            v.w = msg[lo + d + 3] * inv + b[h * D + lo + d + 3];
            *(float4*)(ob + d) = v;
        }
    }
}

// ---------------------------------------------------------------- MLP head + global max
__global__ void mlp_max_kernel(const float* __restrict__ h3,
                               const float* __restrict__ l1w, const float* __restrict__ l1b,
                               const float* __restrict__ l2w, const float* __restrict__ l2b,
                               const float* __restrict__ l3w, const float* __restrict__ l3b,
                               const float* __restrict__ l4w, const float* __restrict__ l4b,
                               unsigned int* __restrict__ maxkey, int N) {
    int tid = blockIdx.x * blockDim.x + threadIdx.x;
    float feat = -3.0e38f;
    if (tid < N) {
        float acc = l4b[0];
        #pragma unroll
        for (int h = 0; h < HEADS; h++) {
            const float4* vp = (const float4*)&h3[((size_t)tid * HEADS + h) * 32];
            float v[32];
            #pragma unroll
            for (int q = 0; q < 8; q++) {
                float4 t = vp[q];
                v[q * 4 + 0] = t.x; v[q * 4 + 1] = t.y; v[q * 4 + 2] = t.z; v[q * 4 + 3] = t.w;
            }
            float y1[16];
            #pragma unroll
            for (int i = 0; i < 16; i++) {
                float s = l1b[i];
                const float* w = &l1w[i * 32];
                #pragma unroll
                for (int k = 0; k < 32; k++) s += v[k] * w[k];
                y1[i] = s > 0.f ? s : 0.01f * s;
            }
            float y2[4];
            #pragma unroll
            for (int i = 0; i < 4; i++) {
                float s = l2b[i];
                const float* w = &l2w[i * 16];
                #pragma unroll
                for (int k = 0; k < 16; k++) s += y1[k] * w[k];
                y2[i] = s > 0.f ? s : 0.01f * s;
            }
            float y3 = l3b[0];
            #pragma unroll
            for (int k = 0; k < 4; k++) y3 += y2[k] * l3w[k];
            acc += y3 * l4w[h];
        }
        feat = acc;
    }
    #pragma unroll
    for (int off = 32; off > 0; off >>= 1)
        feat = fmaxf(feat, __shfl_down(feat, off));
    if ((threadIdx.x & 63) == 0) {
        unsigned int u = __float_as_uint(feat);
        unsigned int key = (u & 0x80000000u) ? ~u : (u | 0x80000000u);
        atomicMax(maxkey, key);
    }
}

__global__ void finalize_kernel(const unsigned int* __restrict__ maxkey, float* __restrict__ out) {
    unsigned int key = *maxkey;
    unsigned int u = (key & 0x80000000u) ? (key & 0x7FFFFFFFu) : ~key;
    out[0] = __uint_as_float(u);
}

// ----------------------------------------------------------------
extern "C" void kernel_launch(void* const* d_in, const int* in_sizes, int n_in,
                              void* d_out, int out_size, void* d_ws, size_t ws_size,
                              hipStream_t stream) {
    const float* node_feats = (const float*)d_in[0];
    const float* edge_feats = (const float*)d_in[1];
    const int* src = (const int*)d_in[2];
    const int* dst = (const int*)d_in[3];
    const float* W1  = (const float*)d_in[4];
    const float* We1 = (const float*)d_in[5];
    const float* al1 = (const float*)d_in[6];
    const float* ar1 = (const float*)d_in[7];
    const float* ae1 = (const float*)d_in[8];
    const float* b1  = (const float*)d_in[9];
    const float* W2  = (const float*)d_in[10];
    const float* We2 = (const float*)d_in[11];
    const float* al2 = (const float*)d_in[12];
    const float* ar2 = (const float*)d_in[13];
    const float* ae2 = (const float*)d_in[14];
    const float* b2  = (const float*)d_in[15];
    const float* W3  = (const float*)d_in[16];
    const float* We3 = (const float*)d_in[17];
    const float* al3 = (const float*)d_in[18];
    const float* ar3 = (const float*)d_in[19];
    const float* ae3 = (const float*)d_in[20];
    const float* b3  = (const float*)d_in[21];
    const float* l1w = (const float*)d_in[22];
    const float* l1b = (const float*)d_in[23];
    const float* l2w = (const float*)d_in[24];
    const float* l2b = (const float*)d_in[25];
    const float* l3w = (const float*)d_in[26];
    const float* l3b = (const float*)d_in[27];
    const float* l4w = (const float*)d_in[28];
    const float* l4b = (const float*)d_in[29];

    const int N = in_sizes[0] / 6;
    const int E = in_sizes[2];
    const int NB = (N + SCAN_BLK - 1) / SCAN_BLK;

    char* ws = (char*)d_ws;
    size_t off = 0;
    auto alloc = [&](size_t bytes) -> void* {
        void* p = ws + off;
        off = (off + bytes + 255) & ~(size_t)255;
        return p;
    };
    int* deg            = (int*)alloc((size_t)N * 4);
    int* bins           = (int*)alloc(64 * 4);
    int* bcnt           = (int*)alloc(64 * 4);
    unsigned int* mkey  = (unsigned int*)alloc(4);
    size_t zero_bytes   = off;  // deg + bins + bcnt + maxkey
    int* bscan          = (int*)alloc(64 * 4);
    int* order          = (int*)alloc((size_t)N * 4);
    int* rank           = (int*)alloc((size_t)E * 4);
    int* row_ptr        = (int*)alloc((size_t)(N + 1) * 4);
    int* partials       = (int*)alloc((size_t)(NB + 1) * 4);
    int2* erec          = (int2*)alloc((size_t)E * 8);
    __half* ft          = (__half*)alloc((size_t)N * 96 * 2);
    float* outb         = (float*)alloc((size_t)N * 96 * 4);
    float* el           = (float*)alloc((size_t)N * 3 * 4);
    float* er           = (float*)alloc((size_t)N * 3 * 4);
    float* ce           = (float*)alloc(9 * 4);

    hipMemsetAsync(d_ws, 0, zero_bytes, stream);

    prep_ce_kernel<<<1, 16, 0, stream>>>(We1, ae1, We2, ae2, We3, ae3, ce);
    hist_rank_kernel<<<(E + 255) / 256, 256, 0, stream>>>(dst, deg, rank, E);
    scan1_kernel<<<NB, SCAN_BLK, 0, stream>>>(deg, row_ptr, partials, N);
    scan2_kernel<<<1, 128, 0, stream>>>(partials, NB);
    scan3_kernel<<<NB, SCAN_BLK, 0, stream>>>(row_ptr, partials, N, NB);
    scatter_kernel<<<(E + 255) / 256, 256, 0, stream>>>(src, dst, edge_feats, row_ptr, rank,
                                                        erec, E);
    // degree-sorted node order
    degbin_hist_kernel<<<(N + 255) / 256, 256, 0, stream>>>(deg, bins, N);
    degbin_scan_kernel<<<1, 64, 0, stream>>>(bins, bscan);
    degbin_scatter_kernel<<<(N + 255) / 256, 256, 0, stream>>>(deg, bscan, bcnt, order, N);

    const int NH = N * HEADS;
    const int gb = (NH + 255) / 256;
    const int gb_agg = (N + 39) / 40;   // 40 nodes per 256-thread block

    // layer 1: 6 -> 8
    node_kernel<6, 8, false><<<gb, 256, 0, stream>>>(node_feats, W1, al1, ar1, ft, el, er, N);
    agg_kernel<8><<<gb_agg, 256, 0, stream>>>(row_ptr, erec, order, ft, el, er, ce + 0, b1, outb, N);
    // layer 2: mean(8) -> 16
    node_kernel<8, 16, true><<<gb, 256, 0, stream>>>(outb, W2, al2, ar2, ft, el, er, N);
    agg_kernel<16><<<gb_agg, 256, 0, stream>>>(row_ptr, erec, order, ft, el, er, ce + 3, b2, outb, N);
    // layer 3: mean(16) -> 32
    node_kernel<16, 32, true><<<gb, 256, 0, stream>>>(outb, W3, al3, ar3, ft, el, er, N);
    agg_kernel<32><<<gb_agg, 256, 0, stream>>>(row_ptr, erec, order, ft, el, er, ce + 6, b3, outb, N);

    // MLP head + global max
    mlp_max_kernel<<<(N + 255) / 256, 256, 0, stream>>>(outb, l1w, l1b, l2w, l2b, l3w, l3b,
                                                        l4w, l4b, mkey, N);
    finalize_kernel<<<1, 1, 0, stream>>>(mkey, (float*)d_out);
}

// Round 8
// 533.894 us; speedup vs baseline: 1.8622x; 1.8622x over previous
//
#include <hip/hip_runtime.h>
#include <hip/hip_bf16.h>
#include <hip/hip_fp16.h>

#define HEADS 3

union HU { uint4 u; __half2 h[4]; };

// ---------------------------------------------------------------- prep: ce[h] = sum_d We[h*D+d] * ae[h*D+d]
__global__ void prep_ce_kernel(const float* __restrict__ We1, const float* __restrict__ ae1,
                               const float* __restrict__ We2, const float* __restrict__ ae2,
                               const float* __restrict__ We3, const float* __restrict__ ae3,
                               float* __restrict__ ce) {
    int t = threadIdx.x;
    if (t >= 9) return;
    int l = t / 3, h = t % 3;
    const float* We = (l == 0) ? We1 : (l == 1) ? We2 : We3;
    const float* ae = (l == 0) ? ae1 : (l == 1) ? ae2 : ae3;
    int D = (l == 0) ? 8 : (l == 1) ? 16 : 32;
    float s = 0.f;
    for (int d = 0; d < D; d++) s += We[h * D + d] * ae[h * D + d];
    ce[t] = s;
}

// ---------------------------------------------------------------- CSR build
// hist + rank in one pass: the atomic's return value is the edge's slot.
__global__ void hist_rank_kernel(const int* __restrict__ dst, int* __restrict__ deg,
                                 int* __restrict__ rank, int E) {
    int tid = blockIdx.x * blockDim.x + threadIdx.x;
    if (tid < E) rank[tid] = atomicAdd(&deg[dst[tid]], 1);
}

#define SCAN_BLK 1024
__global__ void scan1_kernel(const int* __restrict__ deg, int* __restrict__ row_ptr,
                             int* __restrict__ partials, int N) {
    __shared__ int sm[SCAN_BLK];
    int t = threadIdx.x;
    int g = blockIdx.x * SCAN_BLK + t;
    int v = (g < N) ? deg[g] : 0;
    sm[t] = v;
    __syncthreads();
    for (int off = 1; off < SCAN_BLK; off <<= 1) {
        int x = (t >= off) ? sm[t - off] : 0;
        __syncthreads();
        sm[t] += x;
        __syncthreads();
    }
    if (g < N) row_ptr[g] = sm[t] - v;   // exclusive
    if (t == SCAN_BLK - 1) partials[blockIdx.x] = sm[t];
}

__global__ void scan2_kernel(int* __restrict__ partials, int NB) {
    __shared__ int sm[128];
    int t = threadIdx.x;
    int v = (t < NB) ? partials[t] : 0;
    sm[t] = v;
    __syncthreads();
    for (int off = 1; off < 128; off <<= 1) {
        int x = (t >= off) ? sm[t - off] : 0;
        __syncthreads();
        sm[t] += x;
        __syncthreads();
    }
    if (t < NB) partials[t] = sm[t] - v;  // exclusive
    if (t == 127) partials[NB] = sm[127]; // total
}

__global__ void scan3_kernel(int* __restrict__ row_ptr, const int* __restrict__ partials,
                             int N, int NB) {
    int g = blockIdx.x * SCAN_BLK + threadIdx.x;
    if (g < N) row_ptr[g] += partials[blockIdx.x];
    if (blockIdx.x == 0 && threadIdx.x == 0) row_ptr[N] = partials[NB];
}

// atomic-free scatter using precomputed ranks
__global__ void scatter_kernel(const int* __restrict__ src, const int* __restrict__ dst,
                               const float* __restrict__ ef, const int* __restrict__ row_ptr,
                               const int* __restrict__ rank, int2* __restrict__ erec, int E) {
    int tid = blockIdx.x * blockDim.x + threadIdx.x;
    if (tid >= E) return;
    int d = dst[tid];
    int pos = row_ptr[d] + rank[tid];
    int2 r;
    r.x = src[tid];
    r.y = __float_as_int(ef[tid]);
    erec[pos] = r;
}

// ---------------------------------------------------------------- node projection
// Writes ft into PER-HEAD slabs (fth = ft + h*N*D) so per-head agg gathers have
// a compact working set that fits per-XCD L2. tid = h*N + n for coalesced writes.
template <int FIN, int D, bool MEAN_PREV>
__launch_bounds__(256)
__global__ void node_kernel(const float* __restrict__ xin,
                            const float* __restrict__ W,
                            const float* __restrict__ al,
                            const float* __restrict__ ar,
                            __half* __restrict__ ft,     // [3][N][D] fp16 (head-sliced)
                            float* __restrict__ el, float* __restrict__ er,  // [3][N]
                            int N) {
    int tid = blockIdx.x * blockDim.x + threadIdx.x;
    if (tid >= N * HEADS) return;
    int h = tid / N, n = tid - h * N;
    float x[FIN];
    if (MEAN_PREV) {
        #pragma unroll
        for (int k = 0; k < FIN; k++)
            x[k] = (xin[(n * HEADS + 0) * FIN + k] +
                    xin[(n * HEADS + 1) * FIN + k] +
                    xin[(n * HEADS + 2) * FIN + k]) * (1.0f / 3.0f);
    } else {
        #pragma unroll
        for (int k = 0; k < FIN; k++) x[k] = xin[n * FIN + k];
    }
    float fv[D];
    float e_l = 0.f, e_r = 0.f;
    #pragma unroll
    for (int d = 0; d < D; d++) {
        const float* wr = &W[(h * D + d) * FIN];
        float f = 0.f;
        #pragma unroll
        for (int k = 0; k < FIN; k++) f += x[k] * wr[k];
        fv[d] = f;
        e_l += f * al[h * D + d];
        e_r += f * ar[h * D + d];
    }
    uint4* dst16 = (uint4*)(ft + ((size_t)h * N + n) * D);
    #pragma unroll
    for (int q = 0; q < D / 8; q++) {
        HU u;
        #pragma unroll
        for (int j = 0; j < 4; j++)
            u.h[j] = __floats2half2_rn(fv[q * 8 + 2 * j], fv[q * 8 + 2 * j + 1]);
        dst16[q] = u.u;
    }
    el[tid] = e_l;   // tid == h*N + n
    er[tid] = e_r;
}

// ---------------------------------------------------------------- attention + aggregate, ONE HEAD
// 2 lanes (slices) per node; contiguous edge halves; single-pass online softmax;
// pair combine via shfl_xor(,1). Gathers hit the per-head ft slab (N*D*2 bytes).
template <int D, int EB>
__launch_bounds__(256)
__global__ void agg_head_kernel(const int* __restrict__ row_ptr, const int2* __restrict__ erec,
                                const __half* __restrict__ fth,   // [N*D] this head
                                const float* __restrict__ elh,    // [N] this head
                                const float* __restrict__ erh,    // [N] this head
                                const float* __restrict__ ce, int h,
                                const float* __restrict__ b,      // [3*D]
                                float* __restrict__ out,          // [N,3,D]
                                int N) {
    int gtid = blockIdx.x * blockDim.x + threadIdx.x;
    int n = gtid >> 1;
    if (n >= N) return;
    int s = gtid & 1;
    int beg = row_ptr[n], end = row_ptr[n + 1];
    int cnt = end - beg;
    int half = (cnt + 1) >> 1;
    int es = beg + s * half;
    int ee = s ? end : (beg + half);
    float ern = erh[n];
    float ceh = ce[h];

    float m = -3.0e38f, ssum = 0.f;
    float msg[D];
    #pragma unroll
    for (int d = 0; d < D; d++) msg[d] = 0.f;

    int e = es;
    for (; e + EB - 1 < ee; e += EB) {
        int2 r[EB];
        #pragma unroll
        for (int i = 0; i < EB; i++) r[i] = erec[e + i];
        float v[EB];
        #pragma unroll
        for (int i = 0; i < EB; i++) {
            float t = elh[r[i].x] + ern + __int_as_float(r[i].y) * ceh;
            v[i] = t > 0.f ? t : 0.2f * t;
        }
        float cm = v[0];
        #pragma unroll
        for (int i = 1; i < EB; i++) cm = fmaxf(cm, v[i]);
        if (cm > m) {
            float sc = __expf(m - cm);
            ssum *= sc;
            #pragma unroll
            for (int d = 0; d < D; d++) msg[d] *= sc;
            m = cm;
        }
        float x[EB];
        #pragma unroll
        for (int i = 0; i < EB; i++) { x[i] = __expf(v[i] - m); ssum += x[i]; }
        #pragma unroll
        for (int i = 0; i < EB; i++) {
            const uint4* fr = (const uint4*)(fth + (size_t)r[i].x * D);
            #pragma unroll
            for (int q = 0; q < D / 8; q++) {
                HU a; a.u = fr[q];
                #pragma unroll
                for (int j = 0; j < 4; j++) {
                    float2 p = __half22float2(a.h[j]);
                    msg[q * 8 + 2 * j + 0] += x[i] * p.x;
                    msg[q * 8 + 2 * j + 1] += x[i] * p.y;
                }
            }
        }
    }
    for (; e < ee; e++) {
        int2 r = erec[e];
        float t = elh[r.x] + ern + __int_as_float(r.y) * ceh;
        t = t > 0.f ? t : 0.2f * t;
        if (t > m) {
            float sc = __expf(m - t);
            ssum *= sc;
            #pragma unroll
            for (int d = 0; d < D; d++) msg[d] *= sc;
            m = t;
        }
        float x = __expf(t - m);
        ssum += x;
        const uint4* fr = (const uint4*)(fth + (size_t)r.x * D);
        #pragma unroll
        for (int q = 0; q < D / 8; q++) {
            HU a; a.u = fr[q];
            #pragma unroll
            for (int j = 0; j < 4; j++) {
                float2 p = __half22float2(a.h[j]);
                msg[q * 8 + 2 * j + 0] += x * p.x;
                msg[q * 8 + 2 * j + 1] += x * p.y;
            }
        }
    }

    // slice-pair combine (partner = lane ^ 1)
    float om = __shfl_xor(m, 1);
    float osum = __shfl_xor(ssum, 1);
    float M = fmaxf(m, om);
    float sA = __expf(m - M);
    float sB = __expf(om - M);
    float tot = ssum * sA + osum * sB;
    float inv = 1.0f / fmaxf(tot, 1e-9f);
    #pragma unroll
    for (int d = 0; d < D; d++)
        msg[d] = msg[d] * sA + __shfl_xor(msg[d], 1) * sB;

    // slice s stores its half of the output row
    int lo = s * (D / 2);
    float* ob = out + ((size_t)n * HEADS + h) * D + lo;
    #pragma unroll
    for (int d = 0; d < D / 2; d += 4) {
        float4 v;
        v.x = msg[lo + d + 0] * inv + b[h * D + lo + d + 0];
        v.y = msg[lo + d + 1] * inv + b[h * D + lo + d + 1];
        v.z = msg[lo + d + 2] * inv + b[h * D + lo + d + 2];
        v.w = msg[lo + d + 3] * inv + b[h * D + lo + d + 3];
        *(float4*)(ob + d) = v;
    }
}

// ---------------------------------------------------------------- MLP head + global max
__global__ void mlp_max_kernel(const float* __restrict__ h3,
                               const float* __restrict__ l1w, const float* __restrict__ l1b,
                               const float* __restrict__ l2w, const float* __restrict__ l2b,
                               const float* __restrict__ l3w, const float* __restrict__ l3b,
                               const float* __restrict__ l4w, const float* __restrict__ l4b,
                               unsigned int* __restrict__ maxkey, int N) {
    int tid = blockIdx.x * blockDim.x + threadIdx.x;
    float feat = -3.0e38f;
    if (tid < N) {
        float acc = l4b[0];
        #pragma unroll
        for (int h = 0; h < HEADS; h++) {
            const float4* vp = (const float4*)&h3[((size_t)tid * HEADS + h) * 32];
            float v[32];
            #pragma unroll
            for (int q = 0; q < 8; q++) {
                float4 t = vp[q];
                v[q * 4 + 0] = t.x; v[q * 4 + 1] = t.y; v[q * 4 + 2] = t.z; v[q * 4 + 3] = t.w;
            }
            float y1[16];
            #pragma unroll
            for (int i = 0; i < 16; i++) {
                float s = l1b[i];
                const float* w = &l1w[i * 32];
                #pragma unroll
                for (int k = 0; k < 32; k++) s += v[k] * w[k];
                y1[i] = s > 0.f ? s : 0.01f * s;
            }
            float y2[4];
            #pragma unroll
            for (int i = 0; i < 4; i++) {
                float s = l2b[i];
                const float* w = &l2w[i * 16];
                #pragma unroll
                for (int k = 0; k < 16; k++) s += y1[k] * w[k];
                y2[i] = s > 0.f ? s : 0.01f * s;
            }
            float y3 = l3b[0];
            #pragma unroll
            for (int k = 0; k < 4; k++) y3 += y2[k] * l3w[k];
            acc += y3 * l4w[h];
        }
        feat = acc;
    }
    #pragma unroll
    for (int off = 32; off > 0; off >>= 1)
        feat = fmaxf(feat, __shfl_down(feat, off));
    if ((threadIdx.x & 63) == 0) {
        unsigned int u = __float_as_uint(feat);
        unsigned int key = (u & 0x80000000u) ? ~u : (u | 0x80000000u);
        atomicMax(maxkey, key);
    }
}

__global__ void finalize_kernel(const unsigned int* __restrict__ maxkey, float* __restrict__ out) {
    unsigned int key = *maxkey;
    unsigned int u = (key & 0x80000000u) ? (key & 0x7FFFFFFFu) : ~key;
    out[0] = __uint_as_float(u);
}

// ----------------------------------------------------------------
extern "C" void kernel_launch(void* const* d_in, const int* in_sizes, int n_in,
                              void* d_out, int out_size, void* d_ws, size_t ws_size,
                              hipStream_t stream) {
    const float* node_feats = (const float*)d_in[0];
    const float* edge_feats = (const float*)d_in[1];
    const int* src = (const int*)d_in[2];
    const int* dst = (const int*)d_in[3];
    const float* W1  = (const float*)d_in[4];
    const float* We1 = (const float*)d_in[5];
    const float* al1 = (const float*)d_in[6];
    const float* ar1 = (const float*)d_in[7];
    const float* ae1 = (const float*)d_in[8];
    const float* b1  = (const float*)d_in[9];
    const float* W2  = (const float*)d_in[10];
    const float* We2 = (const float*)d_in[11];
    const float* al2 = (const float*)d_in[12];
    const float* ar2 = (const float*)d_in[13];
    const float* ae2 = (const float*)d_in[14];
    const float* b2  = (const float*)d_in[15];
    const float* W3  = (const float*)d_in[16];
    const float* We3 = (const float*)d_in[17];
    const float* al3 = (const float*)d_in[18];
    const float* ar3 = (const float*)d_in[19];
    const float* ae3 = (const float*)d_in[20];
    const float* b3  = (const float*)d_in[21];
    const float* l1w = (const float*)d_in[22];
    const float* l1b = (const float*)d_in[23];
    const float* l2w = (const float*)d_in[24];
    const float* l2b = (const float*)d_in[25];
    const float* l3w = (const float*)d_in[26];
    const float* l3b = (const float*)d_in[27];
    const float* l4w = (const float*)d_in[28];
    const float* l4b = (const float*)d_in[29];

    const int N = in_sizes[0] / 6;
    const int E = in_sizes[2];
    const int NB = (N + SCAN_BLK - 1) / SCAN_BLK;

    char* ws = (char*)d_ws;
    size_t off = 0;
    auto alloc = [&](size_t bytes) -> void* {
        void* p = ws + off;
        off = (off + bytes + 255) & ~(size_t)255;
        return p;
    };
    int* deg            = (int*)alloc((size_t)N * 4);
    unsigned int* mkey  = (unsigned int*)alloc(4);
    size_t zero_bytes   = off;  // deg + maxkey
    int* rank           = (int*)alloc((size_t)E * 4);
    int* row_ptr        = (int*)alloc((size_t)(N + 1) * 4);
    int* partials       = (int*)alloc((size_t)(NB + 1) * 4);
    int2* erec          = (int2*)alloc((size_t)E * 8);
    __half* ft          = (__half*)alloc((size_t)N * 96 * 2);
    float* outb         = (float*)alloc((size_t)N * 96 * 4);
    float* el           = (float*)alloc((size_t)N * 3 * 4);
    float* er           = (float*)alloc((size_t)N * 3 * 4);
    float* ce           = (float*)alloc(9 * 4);

    hipMemsetAsync(d_ws, 0, zero_bytes, stream);

    prep_ce_kernel<<<1, 16, 0, stream>>>(We1, ae1, We2, ae2, We3, ae3, ce);
    hist_rank_kernel<<<(E + 255) / 256, 256, 0, stream>>>(dst, deg, rank, E);
    scan1_kernel<<<NB, SCAN_BLK, 0, stream>>>(deg, row_ptr, partials, N);
    scan2_kernel<<<1, 128, 0, stream>>>(partials, NB);
    scan3_kernel<<<NB, SCAN_BLK, 0, stream>>>(row_ptr, partials, N, NB);
    scatter_kernel<<<(E + 255) / 256, 256, 0, stream>>>(src, dst, edge_feats, row_ptr, rank,
                                                        erec, E);

    const int NH = N * HEADS;
    const int gb = (NH + 255) / 256;
    const int gb_agg = (2 * N + 255) / 256;

    // layer 1: 6 -> 8 (per-head ft slabs of N*8)
    node_kernel<6, 8, false><<<gb, 256, 0, stream>>>(node_feats, W1, al1, ar1, ft, el, er, N);
    for (int h = 0; h < HEADS; h++)
        agg_head_kernel<8, 4><<<gb_agg, 256, 0, stream>>>(
            row_ptr, erec, ft + (size_t)h * N * 8, el + (size_t)h * N, er + (size_t)h * N,
            ce + 0, h, b1, outb, N);
    // layer 2: mean(8) -> 16
    node_kernel<8, 16, true><<<gb, 256, 0, stream>>>(outb, W2, al2, ar2, ft, el, er, N);
    for (int h = 0; h < HEADS; h++)
        agg_head_kernel<16, 4><<<gb_agg, 256, 0, stream>>>(
            row_ptr, erec, ft + (size_t)h * N * 16, el + (size_t)h * N, er + (size_t)h * N,
            ce + 3, h, b2, outb, N);
    // layer 3: mean(16) -> 32
    node_kernel<16, 32, true><<<gb, 256, 0, stream>>>(outb, W3, al3, ar3, ft, el, er, N);
    for (int h = 0; h < HEADS; h++)
        agg_head_kernel<32, 2><<<gb_agg, 256, 0, stream>>>(
            row_ptr, erec, ft + (size_t)h * N * 32, el + (size_t)h * N, er + (size_t)h * N,
            ce + 6, h, b3, outb, N);

    // MLP head + global max
    mlp_max_kernel<<<(N + 255) / 256, 256, 0, stream>>>(outb, l1w, l1b, l2w, l2b, l3w, l3b,
                                                        l4w, l4b, mkey, N);
    finalize_kernel<<<1, 1, 0, stream>>>(mkey, (float*)d_out);
}

// Round 9
// 498.227 us; speedup vs baseline: 1.9955x; 1.0716x over previous
//
#include <hip/hip_runtime.h>
#include <hip/hip_bf16.h>
#include <hip/hip_fp16.h>

#define HEADS 3

union HU { uint4 u; __half2 h[4]; };

// ---------------------------------------------------------------- prep: ce[h] = sum_d We[h*D+d] * ae[h*D+d]
__global__ void prep_ce_kernel(const float* __restrict__ We1, const float* __restrict__ ae1,
                               const float* __restrict__ We2, const float* __restrict__ ae2,
                               const float* __restrict__ We3, const float* __restrict__ ae3,
                               float* __restrict__ ce) {
    int t = threadIdx.x;
    if (t >= 9) return;
    int l = t / 3, h = t % 3;
    const float* We = (l == 0) ? We1 : (l == 1) ? We2 : We3;
    const float* ae = (l == 0) ? ae1 : (l == 1) ? ae2 : ae3;
    int D = (l == 0) ? 8 : (l == 1) ? 16 : 32;
    float s = 0.f;
    for (int d = 0; d < D; d++) s += We[h * D + d] * ae[h * D + d];
    ce[t] = s;
}

// ---------------------------------------------------------------- CSR build
// hist + rank in one pass: the atomic's return value is the edge's slot.
__global__ void hist_rank_kernel(const int* __restrict__ dst, int* __restrict__ deg,
                                 int* __restrict__ rank, int E) {
    int tid = blockIdx.x * blockDim.x + threadIdx.x;
    if (tid < E) rank[tid] = atomicAdd(&deg[dst[tid]], 1);
}

#define SCAN_BLK 1024
__global__ void scan1_kernel(const int* __restrict__ deg, int* __restrict__ row_ptr,
                             int* __restrict__ partials, int N) {
    __shared__ int sm[SCAN_BLK];
    int t = threadIdx.x;
    int g = blockIdx.x * SCAN_BLK + t;
    int v = (g < N) ? deg[g] : 0;
    sm[t] = v;
    __syncthreads();
    for (int off = 1; off < SCAN_BLK; off <<= 1) {
        int x = (t >= off) ? sm[t - off] : 0;
        __syncthreads();
        sm[t] += x;
        __syncthreads();
    }
    if (g < N) row_ptr[g] = sm[t] - v;   // exclusive
    if (t == SCAN_BLK - 1) partials[blockIdx.x] = sm[t];
}

__global__ void scan2_kernel(int* __restrict__ partials, int NB) {
    __shared__ int sm[128];
    int t = threadIdx.x;
    int v = (t < NB) ? partials[t] : 0;
    sm[t] = v;
    __syncthreads();
    for (int off = 1; off < 128; off <<= 1) {
        int x = (t >= off) ? sm[t - off] : 0;
        __syncthreads();
        sm[t] += x;
        __syncthreads();
    }
    if (t < NB) partials[t] = sm[t] - v;  // exclusive
    if (t == 127) partials[NB] = sm[127]; // total
}

__global__ void scan3_kernel(int* __restrict__ row_ptr, const int* __restrict__ partials,
                             int N, int NB) {
    int g = blockIdx.x * SCAN_BLK + threadIdx.x;
    if (g < N) row_ptr[g] += partials[blockIdx.x];
    if (blockIdx.x == 0 && threadIdx.x == 0) row_ptr[N] = partials[NB];
}

// atomic-free scatter using precomputed ranks; non-temporal stores (no reuse soon)
__global__ void scatter_kernel(const int* __restrict__ src, const int* __restrict__ dst,
                               const float* __restrict__ ef, const int* __restrict__ row_ptr,
                               const int* __restrict__ rank, int2* __restrict__ erec, int E) {
    int tid = blockIdx.x * blockDim.x + threadIdx.x;
    if (tid >= E) return;
    int d = dst[tid];
    int pos = row_ptr[d] + rank[tid];
    union { int2 r; long long ll; } u;
    u.r.x = src[tid];
    u.r.y = __float_as_int(ef[tid]);
    __builtin_nontemporal_store(u.ll, (long long*)&erec[pos]);
}

// ---------------------------------------------------------------- node projection: ft (fp16), el, er
// Input is [n][FIN] (node_feats or fused head-mean from previous agg).
template <int FIN, int D>
__launch_bounds__(256)
__global__ void node_kernel(const float* __restrict__ xin,
                            const float* __restrict__ W,
                            const float* __restrict__ al,
                            const float* __restrict__ ar,
                            __half* __restrict__ ft,     // [N,3,D] fp16
                            float* __restrict__ el, float* __restrict__ er,
                            int N) {
    int tid = blockIdx.x * blockDim.x + threadIdx.x;
    if (tid >= N * HEADS) return;
    int n = tid / HEADS, h = tid % HEADS;
    float x[FIN];
    #pragma unroll
    for (int k = 0; k < FIN; k++) x[k] = xin[n * FIN + k];
    float fv[D];
    float e_l = 0.f, e_r = 0.f;
    #pragma unroll
    for (int d = 0; d < D; d++) {
        const float* wr = &W[(h * D + d) * FIN];
        float f = 0.f;
        #pragma unroll
        for (int k = 0; k < FIN; k++) f += x[k] * wr[k];
        fv[d] = f;
        e_l += f * al[h * D + d];
        e_r += f * ar[h * D + d];
    }
    uint4* dst16 = (uint4*)(ft + (size_t)tid * D);
    #pragma unroll
    for (int q = 0; q < D / 8; q++) {
        HU u;
        #pragma unroll
        for (int j = 0; j < 4; j++)
            u.h[j] = __floats2half2_rn(fv[q * 8 + 2 * j], fv[q * 8 + 2 * j + 1]);
        dst16[q] = u.u;
    }
    el[tid] = e_l;
    er[tid] = e_r;
}

// ---------------------------------------------------------------- attention + aggregate
// 6 lanes per node: (slice s in {0,1}) x (head h in {0,1,2}), h innermost so the
// 3 head-lanes gather one contiguous ft node-group; 10 nodes per wave.
// EPI==0: epilogue computes head-mean and writes xmean[n][D] (fuses next layer's input).
// EPI==1: epilogue runs the per-head MLP 32->16->4->1, combines heads, wave-max, atomicMax.
template <int D, int EPI>
__launch_bounds__(256)
__global__ void agg_kernel(const int* __restrict__ row_ptr, const int2* __restrict__ erec,
                           const __half* __restrict__ ft,
                           const float* __restrict__ el, const float* __restrict__ er,
                           const float* __restrict__ ce,   // [3] this layer
                           const float* __restrict__ b,    // [3*D]
                           float* __restrict__ xmean,      // [N,D] (EPI==0)
                           const float* __restrict__ l1w, const float* __restrict__ l1b,
                           const float* __restrict__ l2w, const float* __restrict__ l2b,
                           const float* __restrict__ l3w, const float* __restrict__ l3b,
                           const float* __restrict__ l4w, const float* __restrict__ l4b,
                           unsigned int* __restrict__ maxkey,
                           int N) {
    int w = threadIdx.x >> 6;
    int l = threadIdx.x & 63;
    int wl = l / 6;                 // node slot within wave, 0..9 (l>=60 idle)
    int rem = l - wl * 6;
    int s = rem >= 3 ? 1 : 0;
    int h = rem - s * 3;
    int n = (blockIdx.x * 4 + w) * 10 + wl;
    bool active = (wl < 10) && (n < N);

    float m = -3.0e38f, ssum = 0.f;
    float msg[D];
    #pragma unroll
    for (int d = 0; d < D; d++) msg[d] = 0.f;
    int unit = n * HEADS + h;
    float ceh = ce[h];

    if (active) {
        int beg = row_ptr[n], end = row_ptr[n + 1];
        int cnt = end - beg;
        int half = (cnt + 1) >> 1;
        int es = beg + s * half;
        int ee = s ? end : (beg + half);
        float ern = er[unit];

        int e = es;
        for (; e + 3 < ee; e += 4) {
            int2 r0 = erec[e + 0], r1 = erec[e + 1], r2 = erec[e + 2], r3 = erec[e + 3];
            float v0 = el[r0.x * HEADS + h] + ern + __int_as_float(r0.y) * ceh;
            float v1 = el[r1.x * HEADS + h] + ern + __int_as_float(r1.y) * ceh;
            float v2 = el[r2.x * HEADS + h] + ern + __int_as_float(r2.y) * ceh;
            float v3 = el[r3.x * HEADS + h] + ern + __int_as_float(r3.y) * ceh;
            v0 = v0 > 0.f ? v0 : 0.2f * v0;
            v1 = v1 > 0.f ? v1 : 0.2f * v1;
            v2 = v2 > 0.f ? v2 : 0.2f * v2;
            v3 = v3 > 0.f ? v3 : 0.2f * v3;
            float cm = fmaxf(fmaxf(v0, v1), fmaxf(v2, v3));
            if (cm > m) {
                float sc = __expf(m - cm);
                ssum *= sc;
                #pragma unroll
                for (int d = 0; d < D; d++) msg[d] *= sc;
                m = cm;
            }
            float x0 = __expf(v0 - m), x1 = __expf(v1 - m);
            float x2 = __expf(v2 - m), x3 = __expf(v3 - m);
            ssum += (x0 + x1) + (x2 + x3);
            const uint4* f0 = (const uint4*)(ft + ((size_t)r0.x * HEADS + h) * D);
            const uint4* f1 = (const uint4*)(ft + ((size_t)r1.x * HEADS + h) * D);
            const uint4* f2 = (const uint4*)(ft + ((size_t)r2.x * HEADS + h) * D);
            const uint4* f3 = (const uint4*)(ft + ((size_t)r3.x * HEADS + h) * D);
            #pragma unroll
            for (int q = 0; q < D / 8; q++) {
                HU a0, a1, a2, a3;
                a0.u = f0[q]; a1.u = f1[q]; a2.u = f2[q]; a3.u = f3[q];
                #pragma unroll
                for (int j = 0; j < 4; j++) {
                    float2 p0 = __half22float2(a0.h[j]);
                    float2 p1 = __half22float2(a1.h[j]);
                    float2 p2 = __half22float2(a2.h[j]);
                    float2 p3 = __half22float2(a3.h[j]);
                    msg[q * 8 + 2 * j + 0] += x0 * p0.x + x1 * p1.x + x2 * p2.x + x3 * p3.x;
                    msg[q * 8 + 2 * j + 1] += x0 * p0.y + x1 * p1.y + x2 * p2.y + x3 * p3.y;
                }
            }
        }
        for (; e < ee; e++) {
            int2 r = erec[e];
            float v = el[r.x * HEADS + h] + ern + __int_as_float(r.y) * ceh;
            v = v > 0.f ? v : 0.2f * v;
            if (v > m) {
                float sc = __expf(m - v);
                ssum *= sc;
                #pragma unroll
                for (int d = 0; d < D; d++) msg[d] *= sc;
                m = v;
            }
            float x = __expf(v - m);
            ssum += x;
            const uint4* fr = (const uint4*)(ft + ((size_t)r.x * HEADS + h) * D);
            #pragma unroll
            for (int q = 0; q < D / 8; q++) {
                HU a; a.u = fr[q];
                #pragma unroll
                for (int j = 0; j < 4; j++) {
                    float2 p = __half22float2(a.h[j]);
                    msg[q * 8 + 2 * j + 0] += x * p.x;
                    msg[q * 8 + 2 * j + 1] += x * p.y;
                }
            }
        }
    }

    // slice-pair combine: partner lane at +/-3 (other slice, same head)
    int pl = (s ? (l - 3) : (l + 3)) & 63;
    float om = __shfl(m, pl);
    float osum = __shfl(ssum, pl);
    float M = fmaxf(m, om);
    float sA = __expf(m - M);
    float sB = __expf(om - M);
    float tot = ssum * sA + osum * sB;
    float inv = 1.0f / fmaxf(tot, 1e-9f);
    float o[D];
    #pragma unroll
    for (int d = 0; d < D; d++)
        o[d] = (msg[d] * sA + __shfl(msg[d], pl) * sB) * inv + b[h * D + d];
    // note: both slices now hold the identical full output row o[0..D)

    if (EPI == 0) {
        // head-mean fused: mean over the 3 h-lanes of this (node, slice)
        int g0 = wl * 6 + s * 3;
        #pragma unroll
        for (int d = 0; d < D; d++)
            o[d] = (__shfl(o[d], g0) + __shfl(o[d], g0 + 1) + __shfl(o[d], g0 + 2)) * (1.0f / 3.0f);
        if (active && h == 0) {
            int lo = s * (D / 2);
            float* ob = xmean + (size_t)n * D + lo;
            #pragma unroll
            for (int d = 0; d < D / 2; d += 4) {
                float4 v;
                v.x = o[lo + d + 0]; v.y = o[lo + d + 1];
                v.z = o[lo + d + 2]; v.w = o[lo + d + 3];
                *(float4*)(ob + d) = v;
            }
        }
    } else {
        // fused per-head MLP 32->16->4->1 (leaky 0.01), head-combine, global max.
        // slice s computes y1 rows [s*8, s*8+8).
        float y1[8];
        #pragma unroll
        for (int i = 0; i < 8; i++) {
            int row = s * 8 + i;
            float acc1 = l1b[row];
            const float* wr = &l1w[row * 32];
            #pragma unroll
            for (int k = 0; k < 32; k++) acc1 += o[k] * wr[k];
            y1[i] = acc1 > 0.f ? acc1 : 0.01f * acc1;
        }
        float y2[4];
        #pragma unroll
        for (int i = 0; i < 4; i++) {
            float p = 0.f;
            const float* wr = &l2w[i * 16 + s * 8];
            #pragma unroll
            for (int k = 0; k < 8; k++) p += y1[k] * wr[k];
            p += __shfl(p, pl);                      // add partner slice's half
            p += l2b[i];
            y2[i] = p > 0.f ? p : 0.01f * p;
        }
        float y3 = l3b[0];
        #pragma unroll
        for (int k = 0; k < 4; k++) y3 += y2[k] * l3w[k];
        // combine heads: feat = l4b + sum_h y3_h * l4w[h]
        int g0 = wl * 6 + s * 3;
        float feat = l4b[0];
        #pragma unroll
        for (int hh = 0; hh < 3; hh++) feat += __shfl(y3, g0 + hh) * l4w[hh];
        if (!active) feat = -3.0e38f;
        #pragma unroll
        for (int off = 32; off > 0; off >>= 1)
            feat = fmaxf(feat, __shfl_down(feat, off));
        if (l == 0) {
            unsigned int u = __float_as_uint(feat);
            unsigned int key = (u & 0x80000000u) ? ~u : (u | 0x80000000u);
            atomicMax(maxkey, key);
        }
    }
}

__global__ void finalize_kernel(const unsigned int* __restrict__ maxkey, float* __restrict__ out) {
    unsigned int key = *maxkey;
    unsigned int u = (key & 0x80000000u) ? (key & 0x7FFFFFFFu) : ~key;
    out[0] = __uint_as_float(u);
}

// ----------------------------------------------------------------
extern "C" void kernel_launch(void* const* d_in, const int* in_sizes, int n_in,
                              void* d_out, int out_size, void* d_ws, size_t ws_size,
                              hipStream_t stream) {
    const float* node_feats = (const float*)d_in[0];
    const float* edge_feats = (const float*)d_in[1];
    const int* src = (const int*)d_in[2];
    const int* dst = (const int*)d_in[3];
    const float* W1  = (const float*)d_in[4];
    const float* We1 = (const float*)d_in[5];
    const float* al1 = (const float*)d_in[6];
    const float* ar1 = (const float*)d_in[7];
    const float* ae1 = (const float*)d_in[8];
    const float* b1  = (const float*)d_in[9];
    const float* W2  = (const float*)d_in[10];
    const float* We2 = (const float*)d_in[11];
    const float* al2 = (const float*)d_in[12];
    const float* ar2 = (const float*)d_in[13];
    const float* ae2 = (const float*)d_in[14];
    const float* b2  = (const float*)d_in[15];
    const float* W3  = (const float*)d_in[16];
    const float* We3 = (const float*)d_in[17];
    const float* al3 = (const float*)d_in[18];
    const float* ar3 = (const float*)d_in[19];
    const float* ae3 = (const float*)d_in[20];
    const float* b3  = (const float*)d_in[21];
    const float* l1w = (const float*)d_in[22];
    const float* l1b = (const float*)d_in[23];
    const float* l2w = (const float*)d_in[24];
    const float* l2b = (const float*)d_in[25];
    const float* l3w = (const float*)d_in[26];
    const float* l3b = (const float*)d_in[27];
    const float* l4w = (const float*)d_in[28];
    const float* l4b = (const float*)d_in[29];

    const int N = in_sizes[0] / 6;
    const int E = in_sizes[2];
    const int NB = (N + SCAN_BLK - 1) / SCAN_BLK;

    char* ws = (char*)d_ws;
    size_t off = 0;
    auto alloc = [&](size_t bytes) -> void* {
        void* p = ws + off;
        off = (off + bytes + 255) & ~(size_t)255;
        return p;
    };
    int* deg            = (int*)alloc((size_t)N * 4);
    unsigned int* mkey  = (unsigned int*)alloc(4);
    size_t zero_bytes   = off;  // deg + maxkey
    int* rank           = (int*)alloc((size_t)E * 4);
    int* row_ptr        = (int*)alloc((size_t)(N + 1) * 4);
    int* partials       = (int*)alloc((size_t)(NB + 1) * 4);
    int2* erec          = (int2*)alloc((size_t)E * 8);
    __half* ft          = (__half*)alloc((size_t)N * 96 * 2);
    float* xmean        = (float*)alloc((size_t)N * 16 * 4);  // up to D=16
    float* el           = (float*)alloc((size_t)N * 3 * 4);
    float* er           = (float*)alloc((size_t)N * 3 * 4);
    float* ce           = (float*)alloc(9 * 4);

    hipMemsetAsync(d_ws, 0, zero_bytes, stream);

    prep_ce_kernel<<<1, 16, 0, stream>>>(We1, ae1, We2, ae2, We3, ae3, ce);
    hist_rank_kernel<<<(E + 255) / 256, 256, 0, stream>>>(dst, deg, rank, E);
    scan1_kernel<<<NB, SCAN_BLK, 0, stream>>>(deg, row_ptr, partials, N);
    scan2_kernel<<<1, 128, 0, stream>>>(partials, NB);
    scan3_kernel<<<NB, SCAN_BLK, 0, stream>>>(row_ptr, partials, N, NB);
    scatter_kernel<<<(E + 255) / 256, 256, 0, stream>>>(src, dst, edge_feats, row_ptr, rank,
                                                        erec, E);

    const int NH = N * HEADS;
    const int gb = (NH + 255) / 256;
    const int gb_agg = (N + 39) / 40;   // 40 nodes per 256-thread block

    // layer 1: 6 -> 8, epilogue writes head-mean xmean[N,8]
    node_kernel<6, 8><<<gb, 256, 0, stream>>>(node_feats, W1, al1, ar1, ft, el, er, N);
    agg_kernel<8, 0><<<gb_agg, 256, 0, stream>>>(row_ptr, erec, ft, el, er, ce + 0, b1, xmean,
                                                 nullptr, nullptr, nullptr, nullptr,
                                                 nullptr, nullptr, nullptr, nullptr,
                                                 nullptr, N);
    // layer 2: 8 -> 16, epilogue writes head-mean xmean[N,16]
    node_kernel<8, 16><<<gb, 256, 0, stream>>>(xmean, W2, al2, ar2, ft, el, er, N);
    agg_kernel<16, 0><<<gb_agg, 256, 0, stream>>>(row_ptr, erec, ft, el, er, ce + 3, b2, xmean,
                                                  nullptr, nullptr, nullptr, nullptr,
                                                  nullptr, nullptr, nullptr, nullptr,
                                                  nullptr, N);
    // layer 3: 16 -> 32, epilogue = fused MLP + global max
    node_kernel<16, 32><<<gb, 256, 0, stream>>>(xmean, W3, al3, ar3, ft, el, er, N);
    agg_kernel<32, 1><<<gb_agg, 256, 0, stream>>>(row_ptr, erec, ft, el, er, ce + 6, b3, nullptr,
                                                  l1w, l1b, l2w, l2b, l3w, l3b, l4w, l4b,
                                                  mkey, N);

    finalize_kernel<<<1, 1, 0, stream>>>(mkey, (float*)d_out);
}

// Round 10
// 463.669 us; speedup vs baseline: 2.1442x; 1.0745x over previous
//
#include <hip/hip_runtime.h>
#include <hip/hip_bf16.h>
#include <hip/hip_fp16.h>

#define HEADS 3

union HU { uint4 u; __half2 h[4]; };

// ---------------------------------------------------------------- prep: ce[h] = sum_d We[h*D+d] * ae[h*D+d]
__global__ void prep_ce_kernel(const float* __restrict__ We1, const float* __restrict__ ae1,
                               const float* __restrict__ We2, const float* __restrict__ ae2,
                               const float* __restrict__ We3, const float* __restrict__ ae3,
                               float* __restrict__ ce) {
    int t = threadIdx.x;
    if (t >= 9) return;
    int l = t / 3, h = t % 3;
    const float* We = (l == 0) ? We1 : (l == 1) ? We2 : We3;
    const float* ae = (l == 0) ? ae1 : (l == 1) ? ae2 : ae3;
    int D = (l == 0) ? 8 : (l == 1) ? 16 : 32;
    float s = 0.f;
    for (int d = 0; d < D; d++) s += We[h * D + d] * ae[h * D + d];
    ce[t] = s;
}

// ---------------------------------------------------------------- CSR build
__global__ void hist_rank_kernel(const int* __restrict__ dst, int* __restrict__ deg,
                                 int* __restrict__ rank, int E) {
    int tid = blockIdx.x * blockDim.x + threadIdx.x;
    if (tid < E) rank[tid] = atomicAdd(&deg[dst[tid]], 1);
}

#define SCAN_BLK 1024
__global__ void scan1_kernel(const int* __restrict__ deg, int* __restrict__ row_ptr,
                             int* __restrict__ partials, int N) {
    __shared__ int sm[SCAN_BLK];
    int t = threadIdx.x;
    int g = blockIdx.x * SCAN_BLK + t;
    int v = (g < N) ? deg[g] : 0;
    sm[t] = v;
    __syncthreads();
    for (int off = 1; off < SCAN_BLK; off <<= 1) {
        int x = (t >= off) ? sm[t - off] : 0;
        __syncthreads();
        sm[t] += x;
        __syncthreads();
    }
    if (g < N) row_ptr[g] = sm[t] - v;   // exclusive
    if (t == SCAN_BLK - 1) partials[blockIdx.x] = sm[t];
}

__global__ void scan2_kernel(int* __restrict__ partials, int NB) {
    __shared__ int sm[128];
    int t = threadIdx.x;
    int v = (t < NB) ? partials[t] : 0;
    sm[t] = v;
    __syncthreads();
    for (int off = 1; off < 128; off <<= 1) {
        int x = (t >= off) ? sm[t - off] : 0;
        __syncthreads();
        sm[t] += x;
        __syncthreads();
    }
    if (t < NB) partials[t] = sm[t] - v;  // exclusive
    if (t == 127) partials[NB] = sm[127]; // total
}

__global__ void scan3_kernel(int* __restrict__ row_ptr, const int* __restrict__ partials,
                             int N, int NB) {
    int g = blockIdx.x * SCAN_BLK + threadIdx.x;
    if (g < N) row_ptr[g] += partials[blockIdx.x];
    if (blockIdx.x == 0 && threadIdx.x == 0) row_ptr[N] = partials[NB];
}

// atomic-free scatter using precomputed ranks; non-temporal stores
__global__ void scatter_kernel(const int* __restrict__ src, const int* __restrict__ dst,
                               const float* __restrict__ ef, const int* __restrict__ row_ptr,
                               const int* __restrict__ rank, int2* __restrict__ erec, int E) {
    int tid = blockIdx.x * blockDim.x + threadIdx.x;
    if (tid >= E) return;
    int d = dst[tid];
    int pos = row_ptr[d] + rank[tid];
    union { int2 r; long long ll; } u;
    u.r.x = src[tid];
    u.r.y = __float_as_int(ef[tid]);
    __builtin_nontemporal_store(u.ll, (long long*)&erec[pos]);
}

// ---------------------------------------------------------------- node projection: ft (fp16), el, er
template <int FIN, int D>
__launch_bounds__(256)
__global__ void node_kernel(const float* __restrict__ xin,   // [N,FIN]
                            const float* __restrict__ W,
                            const float* __restrict__ al,
                            const float* __restrict__ ar,
                            __half* __restrict__ ft,     // [N,3,D] fp16
                            float* __restrict__ el, float* __restrict__ er,
                            int N) {
    int tid = blockIdx.x * blockDim.x + threadIdx.x;
    if (tid >= N * HEADS) return;
    int n = tid / HEADS, h = tid % HEADS;
    float x[FIN];
    #pragma unroll
    for (int k = 0; k < FIN; k++) x[k] = xin[n * FIN + k];
    float fv[D];
    float e_l = 0.f, e_r = 0.f;
    #pragma unroll
    for (int d = 0; d < D; d++) {
        const float* wr = &W[(h * D + d) * FIN];
        float f = 0.f;
        #pragma unroll
        for (int k = 0; k < FIN; k++) f += x[k] * wr[k];
        fv[d] = f;
        e_l += f * al[h * D + d];
        e_r += f * ar[h * D + d];
    }
    uint4* dst16 = (uint4*)(ft + (size_t)tid * D);
    #pragma unroll
    for (int q = 0; q < D / 8; q++) {
        HU u;
        #pragma unroll
        for (int j = 0; j < 4; j++)
            u.h[j] = __floats2half2_rn(fv[q * 8 + 2 * j], fv[q * 8 + 2 * j + 1]);
        dst16[q] = u.u;
    }
    el[tid] = e_l;
    er[tid] = e_r;
}

// ---------------------------------------------------------------- attention + aggregate
// 6 lanes per node: (slice s in {0,1}) x (head h in {0,1,2}), h innermost;
// 10 nodes per wave. EPI==0: epilogue writes head-mean xmean[n][D].
// EPI==1: epilogue writes h3 row as fp16 (no heavy fused compute -> loop keeps
// its R4 register shape and 4-edge load batching).
template <int D, int EPI>
__launch_bounds__(256)
__global__ void agg_kernel(const int* __restrict__ row_ptr, const int2* __restrict__ erec,
                           const __half* __restrict__ ft,
                           const float* __restrict__ el, const float* __restrict__ er,
                           const float* __restrict__ ce,   // [3] this layer
                           const float* __restrict__ b,    // [3*D]
                           float* __restrict__ xmean,      // [N,D]   (EPI==0)
                           __half* __restrict__ h3out,     // [N,3,D] (EPI==1)
                           int N) {
    int w = threadIdx.x >> 6;
    int l = threadIdx.x & 63;
    int wl = l / 6;                 // node slot within wave, 0..9 (l>=60 idle)
    int rem = l - wl * 6;
    int s = rem >= 3 ? 1 : 0;
    int h = rem - s * 3;
    int n = (blockIdx.x * 4 + w) * 10 + wl;
    bool active = (wl < 10) && (n < N);

    float m = -3.0e38f, ssum = 0.f;
    float msg[D];
    #pragma unroll
    for (int d = 0; d < D; d++) msg[d] = 0.f;
    int unit = n * HEADS + h;
    float ceh = ce[h];

    if (active) {
        int beg = row_ptr[n], end = row_ptr[n + 1];
        int cnt = end - beg;
        int half = (cnt + 1) >> 1;
        int es = beg + s * half;
        int ee = s ? end : (beg + half);
        float ern = er[unit];

        int e = es;
        for (; e + 3 < ee; e += 4) {
            int2 r0 = erec[e + 0], r1 = erec[e + 1], r2 = erec[e + 2], r3 = erec[e + 3];
            float v0 = el[r0.x * HEADS + h] + ern + __int_as_float(r0.y) * ceh;
            float v1 = el[r1.x * HEADS + h] + ern + __int_as_float(r1.y) * ceh;
            float v2 = el[r2.x * HEADS + h] + ern + __int_as_float(r2.y) * ceh;
            float v3 = el[r3.x * HEADS + h] + ern + __int_as_float(r3.y) * ceh;
            v0 = v0 > 0.f ? v0 : 0.2f * v0;
            v1 = v1 > 0.f ? v1 : 0.2f * v1;
            v2 = v2 > 0.f ? v2 : 0.2f * v2;
            v3 = v3 > 0.f ? v3 : 0.2f * v3;
            float cm = fmaxf(fmaxf(v0, v1), fmaxf(v2, v3));
            if (cm > m) {
                float sc = __expf(m - cm);
                ssum *= sc;
                #pragma unroll
                for (int d = 0; d < D; d++) msg[d] *= sc;
                m = cm;
            }
            float x0 = __expf(v0 - m), x1 = __expf(v1 - m);
            float x2 = __expf(v2 - m), x3 = __expf(v3 - m);
            ssum += (x0 + x1) + (x2 + x3);
            const uint4* f0 = (const uint4*)(ft + ((size_t)r0.x * HEADS + h) * D);
            const uint4* f1 = (const uint4*)(ft + ((size_t)r1.x * HEADS + h) * D);
            const uint4* f2 = (const uint4*)(ft + ((size_t)r2.x * HEADS + h) * D);
            const uint4* f3 = (const uint4*)(ft + ((size_t)r3.x * HEADS + h) * D);
            #pragma unroll
            for (int q = 0; q < D / 8; q++) {
                HU a0, a1, a2, a3;
                a0.u = f0[q]; a1.u = f1[q]; a2.u = f2[q]; a3.u = f3[q];
                #pragma unroll
                for (int j = 0; j < 4; j++) {
                    float2 p0 = __half22float2(a0.h[j]);
                    float2 p1 = __half22float2(a1.h[j]);
                    float2 p2 = __half22float2(a2.h[j]);
                    float2 p3 = __half22float2(a3.h[j]);
                    msg[q * 8 + 2 * j + 0] += x0 * p0.x + x1 * p1.x + x2 * p2.x + x3 * p3.x;
                    msg[q * 8 + 2 * j + 1] += x0 * p0.y + x1 * p1.y + x2 * p2.y + x3 * p3.y;
                }
            }
        }
        for (; e < ee; e++) {
            int2 r = erec[e];
            float v = el[r.x * HEADS + h] + ern + __int_as_float(r.y) * ceh;
            v = v > 0.f ? v : 0.2f * v;
            if (v > m) {
                float sc = __expf(m - v);
                ssum *= sc;
                #pragma unroll
                for (int d = 0; d < D; d++) msg[d] *= sc;
                m = v;
            }
            float x = __expf(v - m);
            ssum += x;
            const uint4* fr = (const uint4*)(ft + ((size_t)r.x * HEADS + h) * D);
            #pragma unroll
            for (int q = 0; q < D / 8; q++) {
                HU a; a.u = fr[q];
                #pragma unroll
                for (int j = 0; j < 4; j++) {
                    float2 p = __half22float2(a.h[j]);
                    msg[q * 8 + 2 * j + 0] += x * p.x;
                    msg[q * 8 + 2 * j + 1] += x * p.y;
                }
            }
        }
    }

    // slice-pair combine: partner lane at +/-3 (other slice, same head), in-place
    int pl = (s ? (l - 3) : (l + 3)) & 63;
    float om = __shfl(m, pl);
    float osum = __shfl(ssum, pl);
    float M = fmaxf(m, om);
    float sA = __expf(m - M);
    float sB = __expf(om - M);
    float tot = ssum * sA + osum * sB;
    float inv = 1.0f / fmaxf(tot, 1e-9f);
    #pragma unroll
    for (int d = 0; d < D; d++)
        msg[d] = (msg[d] * sA + __shfl(msg[d], pl) * sB) * inv + b[h * D + d];
    // both slices now hold the identical full output row msg[0..D)

    if (EPI == 0) {
        // head-mean fused: mean over the 3 h-lanes of this (node, slice)
        int g0 = wl * 6 + s * 3;
        #pragma unroll
        for (int d = 0; d < D; d++)
            msg[d] = (__shfl(msg[d], g0) + __shfl(msg[d], g0 + 1) + __shfl(msg[d], g0 + 2)) * (1.0f / 3.0f);
        if (active && h == 0) {
            int lo = s * (D / 2);
            float* ob = xmean + (size_t)n * D + lo;
            #pragma unroll
            for (int d = 0; d < D / 2; d += 4) {
                float4 v;
                v.x = msg[lo + d + 0]; v.y = msg[lo + d + 1];
                v.z = msg[lo + d + 2]; v.w = msg[lo + d + 3];
                *(float4*)(ob + d) = v;
            }
        }
    } else {
        // write this (n,h) row as fp16; slice s writes its half [lo, lo+D/2)
        if (active) {
            int lo = s * (D / 2);
            __half* hb = h3out + ((size_t)n * HEADS + h) * D + lo;
            #pragma unroll
            for (int q = 0; q < D / 16; q++) {    // D=32: 2 x 8-half chunks per slice
                HU u;
                #pragma unroll
                for (int j = 0; j < 4; j++)
                    u.h[j] = __floats2half2_rn(msg[lo + q * 8 + 2 * j],
                                               msg[lo + q * 8 + 2 * j + 1]);
                *(uint4*)(hb + q * 8) = u.u;
            }
        }
    }
}

// ---------------------------------------------------------------- MLP head + global max (fp16 input)
__global__ void mlp_max_kernel(const __half* __restrict__ h3,   // [N,3,32] fp16
                               const float* __restrict__ l1w, const float* __restrict__ l1b,
                               const float* __restrict__ l2w, const float* __restrict__ l2b,
                               const float* __restrict__ l3w, const float* __restrict__ l3b,
                               const float* __restrict__ l4w, const float* __restrict__ l4b,
                               unsigned int* __restrict__ maxkey, int N) {
    int tid = blockIdx.x * blockDim.x + threadIdx.x;
    float feat = -3.0e38f;
    if (tid < N) {
        float acc = l4b[0];
        #pragma unroll
        for (int h = 0; h < HEADS; h++) {
            const uint4* vp = (const uint4*)(h3 + ((size_t)tid * HEADS + h) * 32);
            float v[32];
            #pragma unroll
            for (int q = 0; q < 4; q++) {
                HU a; a.u = vp[q];
                #pragma unroll
                for (int j = 0; j < 4; j++) {
                    float2 p = __half22float2(a.h[j]);
                    v[q * 8 + 2 * j + 0] = p.x;
                    v[q * 8 + 2 * j + 1] = p.y;
                }
            }
            float y1[16];
            #pragma unroll
            for (int i = 0; i < 16; i++) {
                float s = l1b[i];
                const float* w = &l1w[i * 32];
                #pragma unroll
                for (int k = 0; k < 32; k++) s += v[k] * w[k];
                y1[i] = s > 0.f ? s : 0.01f * s;
            }
            float y2[4];
            #pragma unroll
            for (int i = 0; i < 4; i++) {
                float s = l2b[i];
                const float* w = &l2w[i * 16];
                #pragma unroll
                for (int k = 0; k < 16; k++) s += y1[k] * w[k];
                y2[i] = s > 0.f ? s : 0.01f * s;
            }
            float y3 = l3b[0];
            #pragma unroll
            for (int k = 0; k < 4; k++) y3 += y2[k] * l3w[k];
            acc += y3 * l4w[h];
        }
        feat = acc;
    }
    #pragma unroll
    for (int off = 32; off > 0; off >>= 1)
        feat = fmaxf(feat, __shfl_down(feat, off));
    if ((threadIdx.x & 63) == 0) {
        unsigned int u = __float_as_uint(feat);
        unsigned int key = (u & 0x80000000u) ? ~u : (u | 0x80000000u);
        atomicMax(maxkey, key);
    }
}

__global__ void finalize_kernel(const unsigned int* __restrict__ maxkey, float* __restrict__ out) {
    unsigned int key = *maxkey;
    unsigned int u = (key & 0x80000000u) ? (key & 0x7FFFFFFFu) : ~key;
    out[0] = __uint_as_float(u);
}

// ----------------------------------------------------------------
extern "C" void kernel_launch(void* const* d_in, const int* in_sizes, int n_in,
                              void* d_out, int out_size, void* d_ws, size_t ws_size,
                              hipStream_t stream) {
    const float* node_feats = (const float*)d_in[0];
    const float* edge_feats = (const float*)d_in[1];
    const int* src = (const int*)d_in[2];
    const int* dst = (const int*)d_in[3];
    const float* W1  = (const float*)d_in[4];
    const float* We1 = (const float*)d_in[5];
    const float* al1 = (const float*)d_in[6];
    const float* ar1 = (const float*)d_in[7];
    const float* ae1 = (const float*)d_in[8];
    const float* b1  = (const float*)d_in[9];
    const float* W2  = (const float*)d_in[10];
    const float* We2 = (const float*)d_in[11];
    const float* al2 = (const float*)d_in[12];
    const float* ar2 = (const float*)d_in[13];
    const float* ae2 = (const float*)d_in[14];
    const float* b2  = (const float*)d_in[15];
    const float* W3  = (const float*)d_in[16];
    const float* We3 = (const float*)d_in[17];
    const float* al3 = (const float*)d_in[18];
    const float* ar3 = (const float*)d_in[19];
    const float* ae3 = (const float*)d_in[20];
    const float* b3  = (const float*)d_in[21];
    const float* l1w = (const float*)d_in[22];
    const float* l1b = (const float*)d_in[23];
    const float* l2w = (const float*)d_in[24];
    const float* l2b = (const float*)d_in[25];
    const float* l3w = (const float*)d_in[26];
    const float* l3b = (const float*)d_in[27];
    const float* l4w = (const float*)d_in[28];
    const float* l4b = (const float*)d_in[29];

    const int N = in_sizes[0] / 6;
    const int E = in_sizes[2];
    const int NB = (N + SCAN_BLK - 1) / SCAN_BLK;

    char* ws = (char*)d_ws;
    size_t off = 0;
    auto alloc = [&](size_t bytes) -> void* {
        void* p = ws + off;
        off = (off + bytes + 255) & ~(size_t)255;
        return p;
    };
    int* deg            = (int*)alloc((size_t)N * 4);
    unsigned int* mkey  = (unsigned int*)alloc(4);
    size_t zero_bytes   = off;  // deg + maxkey
    int* rank           = (int*)alloc((size_t)E * 4);
    int* row_ptr        = (int*)alloc((size_t)(N + 1) * 4);
    int* partials       = (int*)alloc((size_t)(NB + 1) * 4);
    int2* erec          = (int2*)alloc((size_t)E * 8);
    __half* ft          = (__half*)alloc((size_t)N * 96 * 2);
    __half* h3          = (__half*)alloc((size_t)N * 96 * 2);
    float* xmean        = (float*)alloc((size_t)N * 16 * 4);  // up to D=16
    float* el           = (float*)alloc((size_t)N * 3 * 4);
    float* er           = (float*)alloc((size_t)N * 3 * 4);
    float* ce           = (float*)alloc(9 * 4);

    hipMemsetAsync(d_ws, 0, zero_bytes, stream);

    prep_ce_kernel<<<1, 16, 0, stream>>>(We1, ae1, We2, ae2, We3, ae3, ce);
    hist_rank_kernel<<<(E + 255) / 256, 256, 0, stream>>>(dst, deg, rank, E);
    scan1_kernel<<<NB, SCAN_BLK, 0, stream>>>(deg, row_ptr, partials, N);
    scan2_kernel<<<1, 128, 0, stream>>>(partials, NB);
    scan3_kernel<<<NB, SCAN_BLK, 0, stream>>>(row_ptr, partials, N, NB);
    scatter_kernel<<<(E + 255) / 256, 256, 0, stream>>>(src, dst, edge_feats, row_ptr, rank,
                                                        erec, E);

    const int NH = N * HEADS;
    const int gb = (NH + 255) / 256;
    const int gb_agg = (N + 39) / 40;   // 40 nodes per 256-thread block

    // layer 1: 6 -> 8, epilogue writes head-mean xmean[N,8]
    node_kernel<6, 8><<<gb, 256, 0, stream>>>(node_feats, W1, al1, ar1, ft, el, er, N);
    agg_kernel<8, 0><<<gb_agg, 256, 0, stream>>>(row_ptr, erec, ft, el, er, ce + 0, b1,
                                                 xmean, nullptr, N);
    // layer 2: 8 -> 16, epilogue writes head-mean xmean[N,16]
    node_kernel<8, 16><<<gb, 256, 0, stream>>>(xmean, W2, al2, ar2, ft, el, er, N);
    agg_kernel<16, 0><<<gb_agg, 256, 0, stream>>>(row_ptr, erec, ft, el, er, ce + 3, b2,
                                                  xmean, nullptr, N);
    // layer 3: 16 -> 32, epilogue writes fp16 h3
    node_kernel<16, 32><<<gb, 256, 0, stream>>>(xmean, W3, al3, ar3, ft, el, er, N);
    agg_kernel<32, 1><<<gb_agg, 256, 0, stream>>>(row_ptr, erec, ft, el, er, ce + 6, b3,
                                                  nullptr, h3, N);

    // MLP head + global max (fp16 h3)
    mlp_max_kernel<<<(N + 255) / 256, 256, 0, stream>>>(h3, l1w, l1b, l2w, l2b, l3w, l3b,
                                                        l4w, l4b, mkey, N);
    finalize_kernel<<<1, 1, 0, stream>>>(mkey, (float*)d_out);
}